// Round 11
// baseline (966.962 us; speedup 1.0000x reference)
//
#include <hip/hip_runtime.h>
#include <hip/hip_bf16.h>
#include <stdint.h>

#define DIM 2048
#define HID 5632

typedef __attribute__((ext_vector_type(8))) short short8;
typedef __attribute__((ext_vector_type(4))) float f32x4;
typedef __attribute__((ext_vector_type(4))) int int4v;
typedef __attribute__((ext_vector_type(4))) unsigned short ushort4v;

__device__ __forceinline__ unsigned short f32_to_bf16_rne(float f) {
    union { float f; unsigned u; } v; v.f = f;
    unsigned u = v.u;
    return (unsigned short)((u + 0x7FFFu + ((u >> 16) & 1u)) >> 16);
}

__device__ __forceinline__ void gload16(const void* g, void* l) {
    __builtin_amdgcn_global_load_lds(
        (const __attribute__((address_space(1))) void*)g,
        (__attribute__((address_space(3))) void*)l,
        16, 0, 0);
}

// ---- dequant down weights (plain row-major, bf16) ----
__global__ void dequant_plain(const int* __restrict__ wq, const float* __restrict__ scale,
                              unsigned short* __restrict__ out, long total, int cols) {
    long n4 = total >> 2;
    long stride = (long)gridDim.x * blockDim.x;
    for (long i = (long)blockIdx.x * blockDim.x + threadIdx.x; i < n4; i += stride) {
        int4v c = ((const int4v*)wq)[i];
        int row = (int)((i << 2) / cols);
        float s = scale[row];
        ushort4v o;
        o.x = f32_to_bf16_rne(((float)c.x - 128.0f) * s);
        o.y = f32_to_bf16_rne(((float)c.y - 128.0f) * s);
        o.z = f32_to_bf16_rne(((float)c.z - 128.0f) * s);
        o.w = f32_to_bf16_rne(((float)c.w - 128.0f) * s);
        ((ushort4v*)out)[i] = o;
    }
}

// ---- dequant gate+up into 16-row-interleaved W' [2*HID][DIM] bf16 ----
__global__ void dequant_gateup(const int* __restrict__ wg, const float* __restrict__ sg,
                               const int* __restrict__ wu, const float* __restrict__ su,
                               unsigned short* __restrict__ out) {
    const long n4 = (long)HID * DIM / 4;
    long stride = (long)gridDim.x * blockDim.x;
    for (long i = (long)blockIdx.x * blockDim.x + threadIdx.x; i < n4; i += stride) {
        int r  = (int)(i >> 9);
        int c4 = (int)(i & 511);
        int rp = ((r >> 4) << 5) + (r & 15);
        float s1 = sg[r], s2 = su[r];
        int4v g = ((const int4v*)wg)[i];
        int4v u = ((const int4v*)wu)[i];
        ushort4v og, ou;
        og.x = f32_to_bf16_rne(((float)g.x - 128.0f) * s1);
        og.y = f32_to_bf16_rne(((float)g.y - 128.0f) * s1);
        og.z = f32_to_bf16_rne(((float)g.z - 128.0f) * s1);
        og.w = f32_to_bf16_rne(((float)g.w - 128.0f) * s1);
        ou.x = f32_to_bf16_rne(((float)u.x - 128.0f) * s2);
        ou.y = f32_to_bf16_rne(((float)u.y - 128.0f) * s2);
        ou.z = f32_to_bf16_rne(((float)u.z - 128.0f) * s2);
        ou.w = f32_to_bf16_rne(((float)u.w - 128.0f) * s2);
        ((ushort4v*)out)[(long)rp * 512 + c4]        = og;
        ((ushort4v*)out)[(long)(rp + 16) * 512 + c4] = ou;
    }
}

// ---- x: f32 -> bf16 ----
__global__ void cast_f32_bf16(const float* __restrict__ in, unsigned short* __restrict__ out, long n) {
    long n4 = n >> 2;
    long stride = (long)gridDim.x * blockDim.x;
    for (long i = (long)blockIdx.x * blockDim.x + threadIdx.x; i < n4; i += stride) {
        f32x4 v = ((const f32x4*)in)[i];
        ushort4v o;
        o.x = f32_to_bf16_rne(v[0]);
        o.y = f32_to_bf16_rne(v[1]);
        o.z = f32_to_bf16_rne(v[2]);
        o.w = f32_to_bf16_rne(v[3]);
        ((ushort4v*)out)[i] = o;
    }
}

// one K-step: counted-vmcnt gate, barrier, ds-reads, 2 MFMA clusters, barrier
#define KSTEP(CURBUF, VMN)                                                            \
    asm volatile("s_waitcnt vmcnt(" #VMN ")" ::: "memory");                           \
    __builtin_amdgcn_s_barrier();                                                     \
    __builtin_amdgcn_sched_barrier(0);                                                \
    {                                                                                 \
        const unsigned short* ap0 = &As[CURBUF][abase + c0];                          \
        const unsigned short* ap1 = &As[CURBUF][abase + c1];                          \
        const unsigned short* bp0 = &Bs[CURBUF][bbase + c0];                          \
        const unsigned short* bp1 = &Bs[CURBUF][bbase + c1];                          \
        short8 a0[8], a1[8], b0[4], b1[4];                                            \
        _Pragma("unroll")                                                             \
        for (int n = 0; n < 4; ++n) {                                                 \
            b0[n] = *(const short8*)(bp0 + (n << 10));                                \
            b1[n] = *(const short8*)(bp1 + (n << 10));                                \
        }                                                                             \
        _Pragma("unroll")                                                             \
        for (int m = 0; m < 8; ++m) {                                                 \
            a0[m] = *(const short8*)(ap0 + (m << 10));                                \
            a1[m] = *(const short8*)(ap1 + (m << 10));                                \
        }                                                                             \
        __builtin_amdgcn_s_setprio(1);                                                \
        _Pragma("unroll")                                                             \
        for (int m = 0; m < 8; ++m)                                                   \
            _Pragma("unroll")                                                         \
            for (int n = 0; n < 4; ++n)                                               \
                acc[m][n] = __builtin_amdgcn_mfma_f32_16x16x32_bf16(a0[m], b0[n], acc[m][n], 0, 0, 0); \
        __builtin_amdgcn_s_setprio(0);                                                \
        __builtin_amdgcn_s_setprio(1);                                                \
        _Pragma("unroll")                                                             \
        for (int m = 0; m < 8; ++m)                                                   \
            _Pragma("unroll")                                                         \
            for (int n = 0; n < 4; ++n)                                               \
                acc[m][n] = __builtin_amdgcn_mfma_f32_16x16x32_bf16(a1[m], b1[n], acc[m][n], 0, 0, 0); \
        __builtin_amdgcn_s_setprio(0);                                                \
    }                                                                                 \
    __builtin_amdgcn_sched_barrier(0);                                                \
    __builtin_amdgcn_s_barrier();                                                     \
    __builtin_amdgcn_sched_barrier(0);

// =====================================================================
// PERSISTENT fused gate+up: 256 blocks (1/CU). Block keeps m-panel
// bx = bid&31 (A reused across tiles, L2/L3-hot) and sweeps n-tiles
// by = (bid>>5) + 8j, j < ntiles (6 for byBase<4 else 5; total 1408).
// The double-buffered K-pipeline NEVER drains across tile boundaries:
// 32 K-tiles/tile is even so LDS parity = kt&1 tile-independently.
// kt=30 stages (j+1,0); kt=31: epilogue (acc->temps->stores, re-zero)
// then stages (j+1,1). vmcnt(8) everywhere; vmcnt(0) only global-last.
// In-order retire check @ tile-j kt=0 top: queue = STAGE(j,0)[8] +
// stores[64] + STAGE(j,1)[8]; vmcnt(8) waits first 72 = STAGE(j,0) ✓.
// =====================================================================
__global__ __launch_bounds__(512, 2) void gemm_gateup(
    const unsigned short* __restrict__ X,
    const unsigned short* __restrict__ Wp,
    unsigned short* __restrict__ H)
{
    __shared__ __attribute__((aligned(16))) unsigned short As[2][256 * 64];
    __shared__ __attribute__((aligned(16))) unsigned short Bs[2][256 * 64];

    const int bid    = blockIdx.x;        // 0..255
    const int bx     = bid & 31;
    const int byBase = bid >> 5;          // 0..7
    const int ntiles = (byBase < 4) ? 6 : 5;
    const int m0     = bx << 8;

    const int tid  = threadIdx.x;
    const int lane = tid & 63;
    const int wid  = tid >> 6;
    const int wr   = wid >> 2;
    const int wc   = wid & 3;
    const int lr   = lane & 15;
    const int kg   = lane >> 4;

    int srow[4], skc[4], sdst[4];
    #pragma unroll
    for (int l = 0; l < 4; ++l) {
        int p = l * 512 + tid;
        srow[l] = p >> 3;
        skc[l]  = (((p & 7) ^ ((p >> 3) & 7)) << 3);
        sdst[l] = p << 3;
    }

    auto STAGE = [&](int n0v, int kt, int buf) {
        const int kk = kt << 6;
        #pragma unroll
        for (int l = 0; l < 4; ++l) {
            gload16(X  + (size_t)(m0  + srow[l]) * DIM + kk + skc[l], &As[buf][sdst[l]]);
            gload16(Wp + (size_t)(n0v + srow[l]) * DIM + kk + skc[l], &Bs[buf][sdst[l]]);
        }
    };

    f32x4 acc[8][4];
    #pragma unroll
    for (int m = 0; m < 8; ++m)
        #pragma unroll
        for (int n = 0; n < 4; ++n) acc[m][n] = (f32x4){0.f, 0.f, 0.f, 0.f};

    const int c0 = ((kg ^ (lr & 7)) << 3);
    const int c1 = (((4 + kg) ^ (lr & 7)) << 3);
    const int abase = (wr * 128 + lr) * 64;
    const int bbase = (wc * 64 + lr) * 64;
    const int lg = lane >> 4;

    {
        const int n00 = byBase << 8;
        STAGE(n00, 0, 0);
        STAGE(n00, 1, 1);
    }

    for (int j = 0; j < ntiles; ++j) {
        const int by   = byBase + (j << 3);
        const int n0   = by << 8;
        const int n0n  = n0 + (8 << 8);
        const bool hasNext = (j + 1 < ntiles);

        #pragma unroll 2
        for (int kt = 0; kt < 30; ++kt) {
            const int cur = kt & 1;
            KSTEP(cur, 8)
            STAGE(n0, kt + 2, cur);
            __builtin_amdgcn_sched_barrier(0);
        }
        // kt = 30 (cur = 0): stage next tile's kt=0
        KSTEP(0, 8)
        if (hasNext) STAGE(n0n, 0, 0);
        __builtin_amdgcn_sched_barrier(0);
        // kt = 31 (cur = 1): MFMA, then epilogue, then stage next tile's kt=1
        if (hasNext) { KSTEP(1, 8) }
        else         { KSTEP(1, 0) }

        // epilogue for tile j: n even = gate, n odd = up (same H cols)
        #pragma unroll
        for (int m = 0; m < 8; ++m) {
            #pragma unroll
            for (int i = 0; i < 2; ++i) {
                f32x4 g = acc[m][2 * i], u = acc[m][2 * i + 1];
                const int col = (by << 7) + wc * 32 + i * 16 + lr;
                #pragma unroll
                for (int e = 0; e < 4; ++e) {
                    const int row = m0 + wr * 128 + m * 16 + lg * 4 + e;
                    float gv = g[e];
                    float sg = gv / (1.0f + __expf(-gv));
                    H[(size_t)row * HID + col] = f32_to_bf16_rne(sg * u[e]);
                }
            }
        }
        #pragma unroll
        for (int m = 0; m < 8; ++m)
            #pragma unroll
            for (int n = 0; n < 4; ++n) acc[m][n] = (f32x4){0.f, 0.f, 0.f, 0.f};

        if (hasNext) STAGE(n0n, 1, 1);
        __builtin_amdgcn_sched_barrier(0);
    }
}

// ---- down: Out[M][DIM] f32 = H @ Wd^T (R2 control, 2-D grid, 1 round) ----
__global__ __launch_bounds__(512, 2) void gemm_down(
    const unsigned short* __restrict__ Hb,
    const unsigned short* __restrict__ Wd,
    float* __restrict__ Out)
{
    __shared__ __attribute__((aligned(16))) unsigned short As[2][256 * 64];
    __shared__ __attribute__((aligned(16))) unsigned short Bs[2][256 * 64];

    const int tid  = threadIdx.x;
    const int lane = tid & 63;
    const int wid  = tid >> 6;
    const int wr   = wid >> 2;
    const int wc   = wid & 3;
    const int m0   = blockIdx.x << 8;
    const int n0   = blockIdx.y << 8;
    const int lr   = lane & 15;
    const int kg   = lane >> 4;

    int srow[4], skc[4], sdst[4];
    #pragma unroll
    for (int l = 0; l < 4; ++l) {
        int p = l * 512 + tid;
        srow[l] = p >> 3;
        skc[l]  = (((p & 7) ^ ((p >> 3) & 7)) << 3);
        sdst[l] = p << 3;
    }

    auto STAGE = [&](int buf, int kt) {
        const int kk = kt << 6;
        #pragma unroll
        for (int l = 0; l < 4; ++l) {
            gload16(Hb + (size_t)(m0 + srow[l]) * HID + kk + skc[l], &As[buf][sdst[l]]);
            gload16(Wd + (size_t)(n0 + srow[l]) * HID + kk + skc[l], &Bs[buf][sdst[l]]);
        }
    };

    f32x4 acc[8][4];
    #pragma unroll
    for (int m = 0; m < 8; ++m)
        #pragma unroll
        for (int n = 0; n < 4; ++n) acc[m][n] = (f32x4){0.f, 0.f, 0.f, 0.f};

    const int c0 = ((kg ^ (lr & 7)) << 3);
    const int c1 = (((4 + kg) ^ (lr & 7)) << 3);
    const int abase = (wr * 128 + lr) * 64;
    const int bbase = (wc * 64 + lr) * 64;

    STAGE(0, 0);
    STAGE(1, 1);

    const int NT = HID / 64;  // 88
    for (int kt = 0; kt < NT; ++kt) {
        const int cur = kt & 1;
        if (kt < NT - 1) { KSTEP(cur, 8) }
        else             { KSTEP(cur, 0) }
        if (kt + 2 < NT) STAGE(cur, kt + 2);
        __builtin_amdgcn_sched_barrier(0);
    }

    const int lg = lane >> 4;
    #pragma unroll
    for (int m = 0; m < 8; ++m) {
        #pragma unroll
        for (int n = 0; n < 4; ++n) {
            const int col = n0 + wc * 64 + n * 16 + lr;
            #pragma unroll
            for (int e = 0; e < 4; ++e) {
                const int row = m0 + wr * 128 + m * 16 + lg * 4 + e;
                Out[(size_t)row * DIM + col] = acc[m][n][e];
            }
        }
    }
}

extern "C" void kernel_launch(void* const* d_in, const int* in_sizes, int n_in,
                              void* d_out, int out_size, void* d_ws, size_t ws_size,
                              hipStream_t stream) {
    const float* x      = (const float*)d_in[0];
    const int* wq_gate  = (const int*)d_in[1];
    const float* s_gate = (const float*)d_in[2];
    const int* wq_up    = (const int*)d_in[3];
    const float* s_up   = (const float*)d_in[4];
    const int* wq_down  = (const int*)d_in[5];
    const float* s_down = (const float*)d_in[6];
    float* out = (float*)d_out;

    const int M = in_sizes[0] / DIM;  // 8192

    // ws layout (elems, bf16): xb [M*DIM] | wgu [2*HID*DIM] (down weights alias) | h [M*HID]
    unsigned short* xb  = (unsigned short*)d_ws;
    unsigned short* wgu = xb + (size_t)M * DIM;
    unsigned short* h   = wgu + (size_t)2 * HID * DIM;

    cast_f32_bf16<<<2048, 256, 0, stream>>>(x, xb, (long)M * DIM);
    dequant_gateup<<<2048, 256, 0, stream>>>(wq_gate, s_gate, wq_up, s_up, wgu);

    // persistent: 256 blocks, each sweeps 5-6 n-tiles with unbroken K-pipeline
    gemm_gateup<<<256, 512, 0, stream>>>(xb, wgu, h);

    dequant_plain<<<2048, 256, 0, stream>>>(wq_down, s_down, wgu, (long)DIM * HID, HID);

    gemm_down<<<dim3(M / 256, DIM / 256), 512, 0, stream>>>(h, wgu, out);
}